// Round 6
// baseline (255.913 us; speedup 1.0000x reference)
//
#include <hip/hip_runtime.h>
#include <math.h>

// Problem constants (reference: B=64, TK=512, NK=256, H=512, fp32 in/out)
constexpr int kB = 64;
constexpr int kTK = 512;
constexpr int kNK = 256;
constexpr int kH = 512;
// scores GEMM grid: tok 256 rowblks x 4 colblks, node 128 x 4
constexpr int kTokGemmBlocks = 256 * 4;   // 1024
constexpr int kNodeGemmBlocks = 128 * 4;  // 512

typedef float f32x4 __attribute__((ext_vector_type(4)));
typedef __bf16 bf16x8 __attribute__((ext_vector_type(8)));
typedef unsigned short u16x8 __attribute__((ext_vector_type(8)));

__device__ __forceinline__ unsigned short f32_to_bf16(float f) {
  return (unsigned short)((__float_as_uint(f) + 0x8000u) >> 16);
}

__device__ __forceinline__ float tanh_fast(float x) {
  float e = __builtin_amdgcn_exp2f(x * 2.8853900817779268f);  // e^{2x}
  return 1.0f - 2.0f * __builtin_amdgcn_rcpf(e + 1.0f);
}

// drain LDS only; leave vmcnt in flight across the barrier
__device__ __forceinline__ void lds_barrier() {
  __builtin_amdgcn_s_waitcnt(0xC07F);
  __builtin_amdgcn_s_barrier();
}

// async global->LDS, 16 B per lane; lds dest = uniform base + lane*16
__device__ __forceinline__ void async_copy16(void* lds, const void* g) {
  __builtin_amdgcn_global_load_lds(
      (const __attribute__((address_space(1))) unsigned int*)g,
      (__attribute__((address_space(3))) unsigned int*)lds, 16, 0, 0);
}

// ---------------------------------------------------------- prep kernel
// blocks [0,512): W transpose->bf16 [n][k]
// blocks [512,1024): dec partials + zero the scores buffers (for atomics)
__global__ __launch_bounds__(256) void prep_kernel(
    const float* __restrict__ Wtok, const float* __restrict__ Wnode,
    unsigned short* __restrict__ WtokT, unsigned short* __restrict__ WnodeT,
    const float* __restrict__ s_t_hat, const float* __restrict__ W_dec,
    float* __restrict__ dec_part, float* __restrict__ scores_base) {
  __shared__ float sm[32 * 33];
  const int tid = threadIdx.x;
  if (blockIdx.x < 512) {
    const int idx = blockIdx.x;
    const int z = idx >> 8, rem = idx & 255;
    const int bx = rem & 15, by = rem >> 4;
    const float* W = z ? Wnode : Wtok;
    unsigned short* T = z ? WnodeT : WtokT;
    const int tx = tid & 31, ty = tid >> 5;
#pragma unroll
    for (int i = 0; i < 4; ++i)
      sm[(ty + 8 * i) * 33 + tx] =
          W[(size_t)(by * 32 + ty + 8 * i) * kH + bx * 32 + tx];
    __syncthreads();
#pragma unroll
    for (int i = 0; i < 4; ++i)
      T[(size_t)(bx * 32 + ty + 8 * i) * kH + by * 32 + tx] =
          f32_to_bf16(sm[tx * 33 + ty + 8 * i]);
  } else {
    const int r = blockIdx.x - 512;
    const int tg = r * 256 + tid;
    if (tg < kB * (kTK + kNK)) scores_base[tg] = 0.f;  // zero scores for atomics
    const int b = r >> 3, s = r & 7;
    if (tid < 128) sm[tid] = s_t_hat[(size_t)b * 1024 + s * 128 + tid];
    __syncthreads();
    float a0 = 0.f, a1 = 0.f;
    const float* w = W_dec + (size_t)(s * 128) * kH;
#pragma unroll 8
    for (int k = 0; k < 128; ++k) {
      a0 = fmaf(sm[k], w[(size_t)k * kH + tid], a0);
      a1 = fmaf(sm[k], w[(size_t)k * kH + tid + 256], a1);
    }
    dec_part[(size_t)(b * 8 + s) * kH + tid] = a0;
    dec_part[(size_t)(b * 8 + s) * kH + tid + 256] = a1;
  }
}

// ---------------------------------------------------------- scores (m97-style)
// 256 threads = 4 waves (2x2). Tile 128 rows x 128 cols, BK=64, 8 chunks.
// Wave computes 64x64 = 4x4 tiles of mfma 16x16x32_bf16.
// B: bf16 WT[n][k] staged to LDS via global_load_lds w=16; the k-slot is
//    XOR-swizzled by (n&7) in the GLOBAL address so frag ds_read_b128 is
//    2-way (free) instead of 16-way.
// A: fp32 load -> bf16 -> LDS frag-major (r4-proven conflict-free);
//    next chunk's A prefetched into VGPRs before compute.
// Epilogue: fused tanh*v partial row-sums, atomicAdd across 4 col-blocks.
__global__ __launch_bounds__(256, 3) void scores_mfma_kernel(
    const float* __restrict__ enc_tok, const float* __restrict__ enc_node,
    const unsigned short* __restrict__ WtokT,
    const unsigned short* __restrict__ WnodeT,
    const float* __restrict__ dec_part, const float* __restrict__ b_dec,
    const float* __restrict__ flow, const float* __restrict__ W_c,
    const float* __restrict__ v_tok, const float* __restrict__ v_node,
    float* __restrict__ scores_tok, float* __restrict__ scores_node) {
  const int tid = threadIdx.x;
  const int wave = tid >> 6, lane = tid & 63;
  const int quad = lane >> 4, l15 = lane & 15;
  const bool is_node = blockIdx.x >= kTokGemmBlocks;
  const int idx = is_node ? (int)blockIdx.x - kTokGemmBlocks : (int)blockIdx.x;
  const int rowblk = idx >> 2, colblk = idx & 3;
  const float* A = is_node ? enc_node : enc_tok;
  const unsigned short* WT = is_node ? WnodeT : WtokT;
  const float* v = is_node ? v_node : v_tok;
  float* scores = is_node ? scores_node : scores_tok;
  const int grow0 = rowblk * 128;  // flat row base (b*ROWS + row)
  const int bn = colblk * 128;     // col base

  __shared__ __align__(16) unsigned short As[8192];  // 16 KB, frag-major
  __shared__ __align__(16) unsigned short Bs[8192];  // 16 KB, [n][k-slot xor]

  const f32x4 fzero = {0.f, 0.f, 0.f, 0.f};
  f32x4 acc[4][4];
#pragma unroll
  for (int i = 0; i < 4; ++i)
#pragma unroll
    for (int j = 0; j < 4; ++j) acc[i][j] = fzero;

  // ---- A staging: thread t -> row = t>>1 (0..127), half = t&1 (which 32-k)
  const int arow = tid >> 1, ahalf = tid & 1;
  const float* aptr = A + (size_t)(grow0 + arow) * kH + ahalf * 32;
  float4 ap[8];
  auto aload = [&](int kc) {
#pragma unroll
    for (int i = 0; i < 8; ++i)
      ap[i] = *(const float4*)(aptr + kc * 64 + i * 4);
  };
  const int fbase = (ahalf * 8 + (arow >> 4)) * 512;
  const int lbase = (arow & 15) * 8;
  auto acommit = [&]() {
#pragma unroll
    for (int q2 = 0; q2 < 4; ++q2) {
      u16x8 h;
      h[0] = f32_to_bf16(ap[q2 * 2].x); h[1] = f32_to_bf16(ap[q2 * 2].y);
      h[2] = f32_to_bf16(ap[q2 * 2].z); h[3] = f32_to_bf16(ap[q2 * 2].w);
      h[4] = f32_to_bf16(ap[q2 * 2 + 1].x); h[5] = f32_to_bf16(ap[q2 * 2 + 1].y);
      h[6] = f32_to_bf16(ap[q2 * 2 + 1].z); h[7] = f32_to_bf16(ap[q2 * 2 + 1].w);
      *(u16x8*)&As[fbase + q2 * 128 + lbase] = h;
    }
  };

  // ---- B staging: round j: nrow = j*32 + (tid>>3), kslot = tid&7,
  // global k-granule = kslot ^ (nrow&7); LDS auto = j*4096B + wave*1024B + lane*16B
  const int nr8 = tid >> 3, kslot = tid & 7;
  auto stageB = [&](int kc) {
#pragma unroll
    for (int j = 0; j < 4; ++j) {
      const int nrow = j * 32 + nr8;
      const unsigned short* g =
          WT + (size_t)(bn + nrow) * kH + kc * 64 + ((kslot ^ (nrow & 7)) * 8);
      async_copy16(&Bs[j * 2048 + wave * 512], g);
    }
  };

  const int wm = (wave >> 1) * 4;   // A frag-block offset (row/16)
  const int wn = (wave & 1) * 64;   // col offset within tile
  auto compute = [&]() {
#pragma unroll
    for (int kh = 0; kh < 2; ++kh) {
      bf16x8 afr[4], bfr[4];
#pragma unroll
      for (int mi = 0; mi < 4; ++mi)
        afr[mi] = *(const bf16x8*)&As[(kh * 8 + wm + mi) * 512 + lane * 8];
#pragma unroll
      for (int ni = 0; ni < 4; ++ni) {
        const int nl = wn + ni * 16 + l15;
        const int s = kh * 4 + quad;
        bfr[ni] = *(const bf16x8*)&Bs[nl * 64 + ((s ^ (nl & 7)) * 8)];
      }
#pragma unroll
      for (int mi = 0; mi < 4; ++mi)
#pragma unroll
        for (int ni = 0; ni < 4; ++ni)
          acc[mi][ni] = __builtin_amdgcn_mfma_f32_16x16x32_bf16(
              afr[mi], bfr[ni], acc[mi][ni], 0, 0, 0);
    }
  };

  aload(0);
  acommit();
  stageB(0);
  aload(1);  // prefetch chunk 1 (hidden behind barrier + chunk-0 compute)
  __syncthreads();

#pragma unroll 1
  for (int kc = 0; kc < 8; ++kc) {
    compute();
    if (kc < 7) {
      lds_barrier();       // readers done (lgkm); vmcnt stays in flight
      acommit();           // A chunk kc+1 (prefetched into VGPRs)
      stageB(kc + 1);
      if (kc < 6) aload(kc + 2);
      __syncthreads();     // B staged (drains vmcnt)
    }
  }

  // ---- fused epilogue; C/D: col = bn+wn+16ni+l15, row = grow0+wm*16+16mi+quad*4+reg
  const int bb = is_node ? (grow0 >> 8) : (grow0 >> 9);  // batch
  float dec4[4], vv4[4], wc4[4];
#pragma unroll
  for (int ni = 0; ni < 4; ++ni) {
    const int col = bn + wn + ni * 16 + l15;
    float d = b_dec[col];
#pragma unroll
    for (int p = 0; p < 8; ++p) d += dec_part[(size_t)(bb * 8 + p) * kH + col];
    dec4[ni] = d;
    vv4[ni] = v[col];
    wc4[ni] = is_node ? W_c[col] : 0.f;
  }
  const int rbase = grow0 + (wave >> 1) * 64;
#pragma unroll
  for (int mi = 0; mi < 4; ++mi) {
#pragma unroll
    for (int reg = 0; reg < 4; ++reg) {
      const int row = rbase + 16 * mi + quad * 4 + reg;  // flat row
      const float fl = is_node ? flow[row] : 0.f;
      float p = 0.f;
#pragma unroll
      for (int ni = 0; ni < 4; ++ni)
        p += tanh_fast(fmaf(fl, wc4[ni], acc[mi][ni][reg] + dec4[ni])) * vv4[ni];
#pragma unroll
      for (int off = 1; off < 16; off <<= 1) p += __shfl_xor(p, off, 64);
      if (l15 == 0) atomicAdd(&scores[row], p);
    }
  }
}

// ---------------------------------------------------------- softmax/mix (+zero flow)
__device__ __forceinline__ float block_sum_512(float v, float* rbuf) {
#pragma unroll
  for (int off = 32; off >= 1; off >>= 1) v += __shfl_xor(v, off, 64);
  if ((threadIdx.x & 63) == 0) rbuf[threadIdx.x >> 6] = v;
  __syncthreads();
  float s = rbuf[0];
#pragma unroll
  for (int w = 1; w < 8; ++w) s += rbuf[w];
  __syncthreads();
  return s;
}

__global__ __launch_bounds__(512) void softmax_mix_kernel(
    const float* __restrict__ scores_node, const float* __restrict__ scores_tok,
    const int* __restrict__ node_to_token,
    const float* __restrict__ mask_tok, const float* __restrict__ mask_node,
    float* __restrict__ out_final, float* __restrict__ out_attn_node,
    float* __restrict__ out_flow) {
  const int b = blockIdx.x, tid = threadIdx.x;
  __shared__ float an_sh[kNK];
  __shared__ float rbuf[8];

  if (tid < kNK) out_flow[b * kNK + tid] = 0.f;  // init for flow2 atomics

  float en = 0.f;
  if (tid < kNK)
    en = expf(scores_node[b * kNK + tid]) * mask_node[b * kNK + tid];
  float sn = block_sum_512(en, rbuf);
  float an = en / sn;
  if (tid < kNK) {
    an_sh[tid] = an;
    out_attn_node[b * kNK + tid] = an;
  }
  __syncthreads();

  const float mt = mask_tok[b * kTK + tid];
  const int idx = node_to_token[b * kTK + tid];
  float eg = expf(an_sh[idx]) * mt;
  float sg = block_sum_512(eg, rbuf);
  float an2t = eg / sg;

  float et = expf(scores_tok[b * kTK + tid]) * mt;
  float st = block_sum_512(et, rbuf);
  float at = et / st;

  out_final[b * kTK + tid] = 0.5f * (at + an2t);
}

// ---------------------------------------------------------- ct_partial + flow1
__global__ __launch_bounds__(512) void ct_flow1_kernel(
    const float* __restrict__ final_attn, const float* __restrict__ enc_tok,
    const float* __restrict__ attn_node, const float* __restrict__ graph,
    float* __restrict__ ctp, float* __restrict__ fp1) {
  const int tid = threadIdx.x;
  if (blockIdx.x < 128) {
    const int b = blockIdx.x >> 1, s = blockIdx.x & 1;
    __shared__ float fa[256];
    if (tid < 256) fa[tid] = final_attn[b * kTK + s * 256 + tid];
    __syncthreads();
    const int h4 = (tid & 127) * 4, tsub = tid >> 7;
    float4 acc = {0.f, 0.f, 0.f, 0.f};
    const float* base =
        enc_tok + ((size_t)(b * kTK + s * 256 + tsub * 64)) * kH + h4;
#pragma unroll 8
    for (int t = 0; t < 64; ++t) {
      float4 e = *(const float4*)(base + (size_t)t * kH);
      const float w = fa[tsub * 64 + t];
      acc.x = fmaf(w, e.x, acc.x); acc.y = fmaf(w, e.y, acc.y);
      acc.z = fmaf(w, e.z, acc.z); acc.w = fmaf(w, e.w, acc.w);
    }
    *(float4*)&ctp[((size_t)(b * 8 + s * 4 + tsub)) * kH + h4] = acc;
  } else {
    const int rr = blockIdx.x - 128;
    const int b = rr >> 2, sl = rr & 3;
    __shared__ float z[64];
    __shared__ float part[8][256];
    if (tid < 64) z[tid] = attn_node[b * kNK + sl * 64 + tid];
    __syncthreads();
    const int m4 = (tid & 63) * 4, nsub = tid >> 6;
    float4 acc = {0.f, 0.f, 0.f, 0.f};
    const float* g =
        graph + ((size_t)(b * kNK + sl * 64 + nsub * 8)) * kNK + m4;
#pragma unroll
    for (int n = 0; n < 8; ++n) {
      float4 gg = *(const float4*)(g + (size_t)n * kNK);
      const float w = z[nsub * 8 + n];
      acc.x = fmaf(w, gg.x, acc.x); acc.y = fmaf(w, gg.y, acc.y);
      acc.z = fmaf(w, gg.z, acc.z); acc.w = fmaf(w, gg.w, acc.w);
    }
    *(float4*)&part[nsub][m4] = acc;
    __syncthreads();
    if (tid < 64) {
      float4 s0 = {0.f, 0.f, 0.f, 0.f};
#pragma unroll
      for (int p = 0; p < 8; ++p) {
        float4 pp = *(const float4*)&part[p][tid * 4];
        s0.x += pp.x; s0.y += pp.y; s0.z += pp.z; s0.w += pp.w;
      }
      *(float4*)&fp1[((size_t)(b * 4 + sl)) * kNK + tid * 4] = s0;
    }
  }
}

// ---------------------------------------------------------- ct_reduce + flow 2-hop
__global__ __launch_bounds__(512) void ct_flow2_kernel(
    const float* __restrict__ ctp, const float* __restrict__ fp1,
    const float* __restrict__ attn_node, const float* __restrict__ graph,
    float* __restrict__ out_ct, float* __restrict__ out_flow) {
  const int tid = threadIdx.x;
  if (blockIdx.x < 64) {
    const int b = blockIdx.x;
    __shared__ float acc_sh[4][512];
    const int h4 = (tid & 127) * 4, part = tid >> 7;
    float4 a = {0.f, 0.f, 0.f, 0.f};
#pragma unroll
    for (int j = 0; j < 2; ++j) {
      float4 c = *(const float4*)&ctp[((size_t)(b * 8 + part * 2 + j)) * kH + h4];
      a.x += c.x; a.y += c.y; a.z += c.z; a.w += c.w;
    }
    *(float4*)&acc_sh[part][h4] = a;
    __syncthreads();
    if (tid < 128) {
      float4 s = {0.f, 0.f, 0.f, 0.f};
#pragma unroll
      for (int p = 0; p < 4; ++p) {
        float4 pp = *(const float4*)&acc_sh[p][tid * 4];
        s.x += pp.x; s.y += pp.y; s.z += pp.z; s.w += pp.w;
      }
      *(float4*)&out_ct[b * kH + tid * 4] = s;
    }
  } else {
    const int rr = blockIdx.x - 64;
    const int b = rr >> 2, sl = rr & 3;
    __shared__ float one_sh[64];
    __shared__ float part2[8][256];
    if (tid < 64) {
      const int n = sl * 64 + tid;
      float one = 0.f;
#pragma unroll
      for (int p = 0; p < 4; ++p) one += fp1[((size_t)(b * 4 + p)) * kNK + n];
      one_sh[tid] = one;
      atomicAdd(&out_flow[b * kNK + n],
                (attn_node[b * kNK + n] + one) * 0.33333f);
    }
    __syncthreads();
    const int m4 = (tid & 63) * 4, nsub = tid >> 6;
    float4 acc = {0.f, 0.f, 0.f, 0.f};
    const float* g =
        graph + ((size_t)(b * kNK + sl * 64 + nsub * 8)) * kNK + m4;
#pragma unroll
    for (int n = 0; n < 8; ++n) {
      float4 gg = *(const float4*)(g + (size_t)n * kNK);
      const float w = one_sh[nsub * 8 + n];
      acc.x = fmaf(w, gg.x, acc.x); acc.y = fmaf(w, gg.y, acc.y);
      acc.z = fmaf(w, gg.z, acc.z); acc.w = fmaf(w, gg.w, acc.w);
    }
    *(float4*)&part2[nsub][m4] = acc;
    __syncthreads();
    if (tid < 64) {
      float4 s = {0.f, 0.f, 0.f, 0.f};
#pragma unroll
      for (int p = 0; p < 8; ++p) {
        float4 pp = *(const float4*)&part2[p][tid * 4];
        s.x += pp.x; s.y += pp.y; s.z += pp.z; s.w += pp.w;
      }
      float* dst = &out_flow[b * kNK + tid * 4];
      atomicAdd(dst + 0, s.x * 0.33333f);
      atomicAdd(dst + 1, s.y * 0.33333f);
      atomicAdd(dst + 2, s.z * 0.33333f);
      atomicAdd(dst + 3, s.w * 0.33333f);
    }
  }
}

// ---------------------------------------------------------------- launch
extern "C" void kernel_launch(void* const* d_in, const int* in_sizes, int n_in,
                              void* d_out, int out_size, void* d_ws, size_t ws_size,
                              hipStream_t stream) {
  (void)in_sizes; (void)n_in; (void)out_size; (void)ws_size;
  const float* s_t_hat  = (const float*)d_in[0];
  const float* enc_tok  = (const float*)d_in[1];
  const float* enc_node = (const float*)d_in[2];
  const int*   n2t      = (const int*)d_in[3];
  const float* mask_tok = (const float*)d_in[4];
  const float* mask_nd  = (const float*)d_in[5];
  const float* graph    = (const float*)d_in[6];
  const float* flow     = (const float*)d_in[7];
  const float* W_c      = (const float*)d_in[8];
  const float* W_tok    = (const float*)d_in[9];
  const float* W_node   = (const float*)d_in[10];
  const float* W_dec    = (const float*)d_in[11];
  const float* b_dec    = (const float*)d_in[12];
  const float* v_tok    = (const float*)d_in[13];
  const float* v_node   = (const float*)d_in[14];

  float* out = (float*)d_out;   // c_t | final_attn | attn_dist_node | flow_out
  float* out_ct        = out;
  float* out_final     = out + kB * kH;
  float* out_attn_node = out + 2 * kB * kH;
  float* out_flow      = out_attn_node + kB * kNK;

  // workspace (float offsets), ~2.03 MB:
  float* ws = (float*)d_ws;
  float* scores_tok  = ws;                    // 32768
  float* scores_node = ws + 32768;            // 16384
  float* dec_part    = ws + 49152;            // 262144 (consumed by scores)
  float* ctp         = dec_part;              // alias: 64*8*512 = 262144
  float* fp1         = ws + 311296;           // 64*4*256 = 65536
  unsigned short* WtokT  = (unsigned short*)(ws + 376832);  // 65536 f
  unsigned short* WnodeT = WtokT + kH * kH;                 // 65536 f

  prep_kernel<<<1024, 256, 0, stream>>>(W_tok, W_node, WtokT, WnodeT,
                                        s_t_hat, W_dec, dec_part, scores_tok);
  scores_mfma_kernel<<<kTokGemmBlocks + kNodeGemmBlocks, 256, 0, stream>>>(
      enc_tok, enc_node, WtokT, WnodeT, dec_part, b_dec, flow, W_c,
      v_tok, v_node, scores_tok, scores_node);
  softmax_mix_kernel<<<kB, 512, 0, stream>>>(scores_node, scores_tok, n2t,
                                             mask_tok, mask_nd, out_final,
                                             out_attn_node, out_flow);
  ct_flow1_kernel<<<384, 512, 0, stream>>>(out_final, enc_tok, out_attn_node,
                                           graph, ctp, fp1);
  ct_flow2_kernel<<<320, 512, 0, stream>>>(ctp, fp1, out_attn_node, graph,
                                           out_ct, out_flow);
}

// Round 7
// 251.578 us; speedup vs baseline: 1.0172x; 1.0172x over previous
//
#include <hip/hip_runtime.h>
#include <math.h>

// Problem constants (reference: B=64, TK=512, NK=256, H=512, fp32 in/out)
constexpr int kB = 64;
constexpr int kTK = 512;
constexpr int kNK = 256;
constexpr int kH = 512;
// scores GEMM: 384 rowblks (tok 256 + node 128) x 4 colblks = 1536 blocks
constexpr int kGemmBlocks = 1536;

typedef float f32x4 __attribute__((ext_vector_type(4)));
typedef __bf16 bf16x8 __attribute__((ext_vector_type(8)));
typedef unsigned short u16x8 __attribute__((ext_vector_type(8)));

__device__ __forceinline__ unsigned short f32_to_bf16(float f) {
  return (unsigned short)((__float_as_uint(f) + 0x8000u) >> 16);
}

__device__ __forceinline__ float tanh_fast(float x) {
  float e = __builtin_amdgcn_exp2f(x * 2.8853900817779268f);  // e^{2x}
  return 1.0f - 2.0f * __builtin_amdgcn_rcpf(e + 1.0f);
}

// drain LDS only; leave vmcnt in flight across the barrier
__device__ __forceinline__ void lds_barrier() {
  __builtin_amdgcn_s_waitcnt(0xC07F);
  __builtin_amdgcn_s_barrier();
}

// async global->LDS, 16 B per lane; lds dest = uniform base + lane*16
__device__ __forceinline__ void async_copy16(void* lds, const void* g) {
  __builtin_amdgcn_global_load_lds(
      (const __attribute__((address_space(1))) unsigned int*)g,
      (__attribute__((address_space(3))) unsigned int*)lds, 16, 0, 0);
}

// ---------------------------------------------------------- prep kernel
// blocks [0,512): W transpose->bf16 [n][k]
// blocks [512,1024): dec partials + zero the scores buffers (for atomics)
__global__ __launch_bounds__(256) void prep_kernel(
    const float* __restrict__ Wtok, const float* __restrict__ Wnode,
    unsigned short* __restrict__ WtokT, unsigned short* __restrict__ WnodeT,
    const float* __restrict__ s_t_hat, const float* __restrict__ W_dec,
    float* __restrict__ dec_part, float* __restrict__ scores_base) {
  __shared__ float sm[32 * 33];
  const int tid = threadIdx.x;
  if (blockIdx.x < 512) {
    const int idx = blockIdx.x;
    const int z = idx >> 8, rem = idx & 255;
    const int bx = rem & 15, by = rem >> 4;
    const float* W = z ? Wnode : Wtok;
    unsigned short* T = z ? WnodeT : WtokT;
    const int tx = tid & 31, ty = tid >> 5;
#pragma unroll
    for (int i = 0; i < 4; ++i)
      sm[(ty + 8 * i) * 33 + tx] =
          W[(size_t)(by * 32 + ty + 8 * i) * kH + bx * 32 + tx];
    __syncthreads();
#pragma unroll
    for (int i = 0; i < 4; ++i)
      T[(size_t)(bx * 32 + ty + 8 * i) * kH + by * 32 + tx] =
          f32_to_bf16(sm[tx * 33 + ty + 8 * i]);
  } else {
    const int r = blockIdx.x - 512;
    const int tg = r * 256 + tid;
    if (tg < kB * (kTK + kNK)) scores_base[tg] = 0.f;  // zero scores for atomics
    const int b = r >> 3, s = r & 7;
    if (tid < 128) sm[tid] = s_t_hat[(size_t)b * 1024 + s * 128 + tid];
    __syncthreads();
    float a0 = 0.f, a1 = 0.f;
    const float* w = W_dec + (size_t)(s * 128) * kH;
#pragma unroll 8
    for (int k = 0; k < 128; ++k) {
      a0 = fmaf(sm[k], w[(size_t)k * kH + tid], a0);
      a1 = fmaf(sm[k], w[(size_t)k * kH + tid + 256], a1);
    }
    dec_part[(size_t)(b * 8 + s) * kH + tid] = a0;
    dec_part[(size_t)(b * 8 + s) * kH + tid + 256] = a1;
  }
}

// ---------------------------------------------------------- scores (m97-style)
// 256 threads = 4 waves (2x2). Tile 128 rows x 128 cols, BK=64, 8 chunks.
// XCD-aware decode: the 4 colblocks of one rowblk map to the SAME XCD
// (idx & 7 = xcd, round-robin dispatch) so colblocks 1..3 hit that XCD's L2
// for the shared fp32 A-tile instead of refetching from HBM.
__global__ __launch_bounds__(256, 3) void scores_mfma_kernel(
    const float* __restrict__ enc_tok, const float* __restrict__ enc_node,
    const unsigned short* __restrict__ WtokT,
    const unsigned short* __restrict__ WnodeT,
    const float* __restrict__ dec_part, const float* __restrict__ b_dec,
    const float* __restrict__ flow, const float* __restrict__ W_c,
    const float* __restrict__ v_tok, const float* __restrict__ v_node,
    float* __restrict__ scores_tok, float* __restrict__ scores_node) {
  const int tid = threadIdx.x;
  const int wave = tid >> 6, lane = tid & 63;
  const int quad = lane >> 4, l15 = lane & 15;
  // XCD-grouped decode: same rowblk's colblocks share idx%8
  const int xcd = blockIdx.x & 7, slot = blockIdx.x >> 3;
  const int colblk = slot & 3;
  const int rowblk_g = xcd + 8 * (slot >> 2);  // 0..383
  const bool is_node = rowblk_g >= 256;
  const int rowblk = is_node ? rowblk_g - 256 : rowblk_g;
  const float* A = is_node ? enc_node : enc_tok;
  const unsigned short* WT = is_node ? WnodeT : WtokT;
  const float* v = is_node ? v_node : v_tok;
  float* scores = is_node ? scores_node : scores_tok;
  const int grow0 = rowblk * 128;  // flat row base (b*ROWS + row)
  const int bn = colblk * 128;     // col base

  __shared__ __align__(16) unsigned short As[8192];  // 16 KB, frag-major
  __shared__ __align__(16) unsigned short Bs[8192];  // 16 KB, [n][k-slot xor]

  const f32x4 fzero = {0.f, 0.f, 0.f, 0.f};
  f32x4 acc[4][4];
#pragma unroll
  for (int i = 0; i < 4; ++i)
#pragma unroll
    for (int j = 0; j < 4; ++j) acc[i][j] = fzero;

  // ---- A staging: thread t -> row = t>>1 (0..127), half = t&1 (which 32-k)
  const int arow = tid >> 1, ahalf = tid & 1;
  const float* aptr = A + (size_t)(grow0 + arow) * kH + ahalf * 32;
  float4 ap[8];
  auto aload = [&](int kc) {
#pragma unroll
    for (int i = 0; i < 8; ++i)
      ap[i] = *(const float4*)(aptr + kc * 64 + i * 4);
  };
  const int fbase = (ahalf * 8 + (arow >> 4)) * 512;
  const int lbase = (arow & 15) * 8;
  auto acommit = [&]() {
#pragma unroll
    for (int q2 = 0; q2 < 4; ++q2) {
      u16x8 h;
      h[0] = f32_to_bf16(ap[q2 * 2].x); h[1] = f32_to_bf16(ap[q2 * 2].y);
      h[2] = f32_to_bf16(ap[q2 * 2].z); h[3] = f32_to_bf16(ap[q2 * 2].w);
      h[4] = f32_to_bf16(ap[q2 * 2 + 1].x); h[5] = f32_to_bf16(ap[q2 * 2 + 1].y);
      h[6] = f32_to_bf16(ap[q2 * 2 + 1].z); h[7] = f32_to_bf16(ap[q2 * 2 + 1].w);
      *(u16x8*)&As[fbase + q2 * 128 + lbase] = h;
    }
  };

  // ---- B staging: round j: nrow = j*32 + (tid>>3), kslot = tid&7,
  // global k-granule = kslot ^ (nrow&7); LDS auto = j*4096B + wave*1024B + lane*16B
  const int nr8 = tid >> 3, kslot = tid & 7;
  auto stageB = [&](int kc) {
#pragma unroll
    for (int j = 0; j < 4; ++j) {
      const int nrow = j * 32 + nr8;
      const unsigned short* g =
          WT + (size_t)(bn + nrow) * kH + kc * 64 + ((kslot ^ (nrow & 7)) * 8);
      async_copy16(&Bs[j * 2048 + wave * 512], g);
    }
  };

  const int wm = (wave >> 1) * 4;   // A frag-block offset (row/16)
  const int wn = (wave & 1) * 64;   // col offset within tile
  auto compute = [&]() {
#pragma unroll
    for (int kh = 0; kh < 2; ++kh) {
      bf16x8 afr[4], bfr[4];
#pragma unroll
      for (int mi = 0; mi < 4; ++mi)
        afr[mi] = *(const bf16x8*)&As[(kh * 8 + wm + mi) * 512 + lane * 8];
#pragma unroll
      for (int ni = 0; ni < 4; ++ni) {
        const int nl = wn + ni * 16 + l15;
        const int s = kh * 4 + quad;
        bfr[ni] = *(const bf16x8*)&Bs[nl * 64 + ((s ^ (nl & 7)) * 8)];
      }
#pragma unroll
      for (int mi = 0; mi < 4; ++mi)
#pragma unroll
        for (int ni = 0; ni < 4; ++ni)
          acc[mi][ni] = __builtin_amdgcn_mfma_f32_16x16x32_bf16(
              afr[mi], bfr[ni], acc[mi][ni], 0, 0, 0);
    }
  };

  aload(0);
  acommit();
  stageB(0);
  aload(1);  // prefetch chunk 1 (hidden behind barrier + chunk-0 compute)
  __syncthreads();

#pragma unroll 1
  for (int kc = 0; kc < 8; ++kc) {
    compute();
    if (kc < 7) {
      lds_barrier();       // readers done (lgkm); vmcnt stays in flight
      acommit();           // A chunk kc+1 (prefetched into VGPRs)
      stageB(kc + 1);
      if (kc < 6) aload(kc + 2);
      __syncthreads();     // B staged (drains vmcnt)
    }
  }

  // ---- fused epilogue; C/D: col = bn+wn+16ni+l15, row = grow0+..+16mi+quad*4+reg
  const int bb = is_node ? (grow0 >> 8) : (grow0 >> 9);  // batch
  float dec4[4], vv4[4], wc4[4];
#pragma unroll
  for (int ni = 0; ni < 4; ++ni) {
    const int col = bn + wn + ni * 16 + l15;
    float d = b_dec[col];
#pragma unroll
    for (int p = 0; p < 8; ++p) d += dec_part[(size_t)(bb * 8 + p) * kH + col];
    dec4[ni] = d;
    vv4[ni] = v[col];
    wc4[ni] = is_node ? W_c[col] : 0.f;
  }
  const int rbase = grow0 + (wave >> 1) * 64;
#pragma unroll
  for (int mi = 0; mi < 4; ++mi) {
#pragma unroll
    for (int reg = 0; reg < 4; ++reg) {
      const int row = rbase + 16 * mi + quad * 4 + reg;  // flat row
      const float fl = is_node ? flow[row] : 0.f;
      float p = 0.f;
#pragma unroll
      for (int ni = 0; ni < 4; ++ni)
        p += tanh_fast(fmaf(fl, wc4[ni], acc[mi][ni][reg] + dec4[ni])) * vv4[ni];
#pragma unroll
      for (int off = 1; off < 16; off <<= 1) p += __shfl_xor(p, off, 64);
      if (l15 == 0) atomicAdd(&scores[row], p);
    }
  }
}

// ---------------------------------------------------------- softmax/mix (+zero flow)
__device__ __forceinline__ float block_sum_512(float v, float* rbuf) {
#pragma unroll
  for (int off = 32; off >= 1; off >>= 1) v += __shfl_xor(v, off, 64);
  if ((threadIdx.x & 63) == 0) rbuf[threadIdx.x >> 6] = v;
  __syncthreads();
  float s = rbuf[0];
#pragma unroll
  for (int w = 1; w < 8; ++w) s += rbuf[w];
  __syncthreads();
  return s;
}

__device__ __forceinline__ float2 block_sum2_512(float a, float b, float* rbuf) {
#pragma unroll
  for (int off = 32; off >= 1; off >>= 1) {
    a += __shfl_xor(a, off, 64);
    b += __shfl_xor(b, off, 64);
  }
  if ((threadIdx.x & 63) == 0) {
    rbuf[(threadIdx.x >> 6) * 2] = a;
    rbuf[(threadIdx.x >> 6) * 2 + 1] = b;
  }
  __syncthreads();
  float sa = 0.f, sb = 0.f;
#pragma unroll
  for (int w = 0; w < 8; ++w) { sa += rbuf[w * 2]; sb += rbuf[w * 2 + 1]; }
  return make_float2(sa, sb);
}

__global__ __launch_bounds__(512) void softmax_mix_kernel(
    const float* __restrict__ scores_node, const float* __restrict__ scores_tok,
    const int* __restrict__ node_to_token,
    const float* __restrict__ mask_tok, const float* __restrict__ mask_node,
    float* __restrict__ out_final, float* __restrict__ out_attn_node,
    float* __restrict__ out_flow) {
  const int b = blockIdx.x, tid = threadIdx.x;
  __shared__ float an_sh[kNK];
  __shared__ float rbuf[16];

  if (tid < kNK) out_flow[b * kNK + tid] = 0.f;  // init for flow2 atomics

  float en = 0.f;
  if (tid < kNK)
    en = expf(scores_node[b * kNK + tid]) * mask_node[b * kNK + tid];
  float sn = block_sum_512(en, rbuf);
  float an = en / sn;
  if (tid < kNK) {
    an_sh[tid] = an;
    out_attn_node[b * kNK + tid] = an;
  }
  __syncthreads();

  const float mt = mask_tok[b * kTK + tid];
  const int idx = node_to_token[b * kTK + tid];
  float eg = expf(an_sh[idx]) * mt;
  float et = expf(scores_tok[b * kTK + tid]) * mt;
  float2 s2 = block_sum2_512(eg, et, rbuf);
  out_final[b * kTK + tid] = 0.5f * (eg / s2.x + et / s2.y);
}

// ---------------------------------------------------------- ct_partial + flow1
__global__ __launch_bounds__(512) void ct_flow1_kernel(
    const float* __restrict__ final_attn, const float* __restrict__ enc_tok,
    const float* __restrict__ attn_node, const float* __restrict__ graph,
    float* __restrict__ ctp, float* __restrict__ fp1) {
  const int tid = threadIdx.x;
  if (blockIdx.x < 128) {
    const int b = blockIdx.x >> 1, s = blockIdx.x & 1;
    __shared__ float fa[256];
    if (tid < 256) fa[tid] = final_attn[b * kTK + s * 256 + tid];
    __syncthreads();
    const int h4 = (tid & 127) * 4, tsub = tid >> 7;
    float4 a0 = {0.f, 0.f, 0.f, 0.f}, a1 = {0.f, 0.f, 0.f, 0.f};
    const float* base =
        enc_tok + ((size_t)(b * kTK + s * 256 + tsub * 64)) * kH + h4;
#pragma unroll 4
    for (int t = 0; t < 64; t += 2) {
      float4 e0 = *(const float4*)(base + (size_t)t * kH);
      float4 e1 = *(const float4*)(base + (size_t)(t + 1) * kH);
      const float w0 = fa[tsub * 64 + t], w1 = fa[tsub * 64 + t + 1];
      a0.x = fmaf(w0, e0.x, a0.x); a0.y = fmaf(w0, e0.y, a0.y);
      a0.z = fmaf(w0, e0.z, a0.z); a0.w = fmaf(w0, e0.w, a0.w);
      a1.x = fmaf(w1, e1.x, a1.x); a1.y = fmaf(w1, e1.y, a1.y);
      a1.z = fmaf(w1, e1.z, a1.z); a1.w = fmaf(w1, e1.w, a1.w);
    }
    float4 acc = {a0.x + a1.x, a0.y + a1.y, a0.z + a1.z, a0.w + a1.w};
    *(float4*)&ctp[((size_t)(b * 8 + s * 4 + tsub)) * kH + h4] = acc;
  } else {
    const int rr = blockIdx.x - 128;
    const int b = rr >> 2, sl = rr & 3;
    __shared__ float z[64];
    __shared__ float part[8][256];
    if (tid < 64) z[tid] = attn_node[b * kNK + sl * 64 + tid];
    __syncthreads();
    const int m4 = (tid & 63) * 4, nsub = tid >> 6;
    float4 acc = {0.f, 0.f, 0.f, 0.f};
    const float* g =
        graph + ((size_t)(b * kNK + sl * 64 + nsub * 8)) * kNK + m4;
#pragma unroll
    for (int n = 0; n < 8; ++n) {
      float4 gg = *(const float4*)(g + (size_t)n * kNK);
      const float w = z[nsub * 8 + n];
      acc.x = fmaf(w, gg.x, acc.x); acc.y = fmaf(w, gg.y, acc.y);
      acc.z = fmaf(w, gg.z, acc.z); acc.w = fmaf(w, gg.w, acc.w);
    }
    *(float4*)&part[nsub][m4] = acc;
    __syncthreads();
    if (tid < 64) {
      float4 s0 = {0.f, 0.f, 0.f, 0.f};
#pragma unroll
      for (int p = 0; p < 8; ++p) {
        float4 pp = *(const float4*)&part[p][tid * 4];
        s0.x += pp.x; s0.y += pp.y; s0.z += pp.z; s0.w += pp.w;
      }
      *(float4*)&fp1[((size_t)(b * 4 + sl)) * kNK + tid * 4] = s0;
    }
  }
}

// ---------------------------------------------------------- ct_reduce + flow 2-hop
__global__ __launch_bounds__(512) void ct_flow2_kernel(
    const float* __restrict__ ctp, const float* __restrict__ fp1,
    const float* __restrict__ attn_node, const float* __restrict__ graph,
    float* __restrict__ out_ct, float* __restrict__ out_flow) {
  const int tid = threadIdx.x;
  if (blockIdx.x < 64) {
    const int b = blockIdx.x;
    __shared__ float acc_sh[4][512];
    const int h4 = (tid & 127) * 4, part = tid >> 7;
    float4 a = {0.f, 0.f, 0.f, 0.f};
#pragma unroll
    for (int j = 0; j < 2; ++j) {
      float4 c = *(const float4*)&ctp[((size_t)(b * 8 + part * 2 + j)) * kH + h4];
      a.x += c.x; a.y += c.y; a.z += c.z; a.w += c.w;
    }
    *(float4*)&acc_sh[part][h4] = a;
    __syncthreads();
    if (tid < 128) {
      float4 s = {0.f, 0.f, 0.f, 0.f};
#pragma unroll
      for (int p = 0; p < 4; ++p) {
        float4 pp = *(const float4*)&acc_sh[p][tid * 4];
        s.x += pp.x; s.y += pp.y; s.z += pp.z; s.w += pp.w;
      }
      *(float4*)&out_ct[b * kH + tid * 4] = s;
    }
  } else {
    const int rr = blockIdx.x - 64;
    const int b = rr >> 2, sl = rr & 3;
    __shared__ float one_sh[64];
    __shared__ float part2[8][256];
    if (tid < 64) {
      const int n = sl * 64 + tid;
      float one = 0.f;
#pragma unroll
      for (int p = 0; p < 4; ++p) one += fp1[((size_t)(b * 4 + p)) * kNK + n];
      one_sh[tid] = one;
      atomicAdd(&out_flow[b * kNK + n],
                (attn_node[b * kNK + n] + one) * 0.33333f);
    }
    __syncthreads();
    const int m4 = (tid & 63) * 4, nsub = tid >> 6;
    float4 acc = {0.f, 0.f, 0.f, 0.f};
    const float* g =
        graph + ((size_t)(b * kNK + sl * 64 + nsub * 8)) * kNK + m4;
#pragma unroll
    for (int n = 0; n < 8; ++n) {
      float4 gg = *(const float4*)(g + (size_t)n * kNK);
      const float w = one_sh[nsub * 8 + n];
      acc.x = fmaf(w, gg.x, acc.x); acc.y = fmaf(w, gg.y, acc.y);
      acc.z = fmaf(w, gg.z, acc.z); acc.w = fmaf(w, gg.w, acc.w);
    }
    *(float4*)&part2[nsub][m4] = acc;
    __syncthreads();
    if (tid < 64) {
      float4 s = {0.f, 0.f, 0.f, 0.f};
#pragma unroll
      for (int p = 0; p < 8; ++p) {
        float4 pp = *(const float4*)&part2[p][tid * 4];
        s.x += pp.x; s.y += pp.y; s.z += pp.z; s.w += pp.w;
      }
      float* dst = &out_flow[b * kNK + tid * 4];
      atomicAdd(dst + 0, s.x * 0.33333f);
      atomicAdd(dst + 1, s.y * 0.33333f);
      atomicAdd(dst + 2, s.z * 0.33333f);
      atomicAdd(dst + 3, s.w * 0.33333f);
    }
  }
}

// ---------------------------------------------------------------- launch
extern "C" void kernel_launch(void* const* d_in, const int* in_sizes, int n_in,
                              void* d_out, int out_size, void* d_ws, size_t ws_size,
                              hipStream_t stream) {
  (void)in_sizes; (void)n_in; (void)out_size; (void)ws_size;
  const float* s_t_hat  = (const float*)d_in[0];
  const float* enc_tok  = (const float*)d_in[1];
  const float* enc_node = (const float*)d_in[2];
  const int*   n2t      = (const int*)d_in[3];
  const float* mask_tok = (const float*)d_in[4];
  const float* mask_nd  = (const float*)d_in[5];
  const float* graph    = (const float*)d_in[6];
  const float* flow     = (const float*)d_in[7];
  const float* W_c      = (const float*)d_in[8];
  const float* W_tok    = (const float*)d_in[9];
  const float* W_node   = (const float*)d_in[10];
  const float* W_dec    = (const float*)d_in[11];
  const float* b_dec    = (const float*)d_in[12];
  const float* v_tok    = (const float*)d_in[13];
  const float* v_node   = (const float*)d_in[14];

  float* out = (float*)d_out;   // c_t | final_attn | attn_dist_node | flow_out
  float* out_ct        = out;
  float* out_final     = out + kB * kH;
  float* out_attn_node = out + 2 * kB * kH;
  float* out_flow      = out_attn_node + kB * kNK;

  // workspace (float offsets), ~2.03 MB:
  float* ws = (float*)d_ws;
  float* scores_tok  = ws;                    // 32768
  float* scores_node = ws + 32768;            // 16384
  float* dec_part    = ws + 49152;            // 262144 (consumed by scores)
  float* ctp         = dec_part;              // alias: 64*8*512 = 262144
  float* fp1         = ws + 311296;           // 64*4*256 = 65536
  unsigned short* WtokT  = (unsigned short*)(ws + 376832);  // 65536 f
  unsigned short* WnodeT = WtokT + kH * kH;                 // 65536 f

  prep_kernel<<<1024, 256, 0, stream>>>(W_tok, W_node, WtokT, WnodeT,
                                        s_t_hat, W_dec, dec_part, scores_tok);
  scores_mfma_kernel<<<kGemmBlocks, 256, 0, stream>>>(
      enc_tok, enc_node, WtokT, WnodeT, dec_part, b_dec, flow, W_c,
      v_tok, v_node, scores_tok, scores_node);
  softmax_mix_kernel<<<kB, 512, 0, stream>>>(scores_node, scores_tok, n2t,
                                             mask_tok, mask_nd, out_final,
                                             out_attn_node, out_flow);
  ct_flow1_kernel<<<384, 512, 0, stream>>>(out_final, enc_tok, out_attn_node,
                                           graph, ctp, fp1);
  ct_flow2_kernel<<<320, 512, 0, stream>>>(ctp, fp1, out_attn_node, graph,
                                           out_ct, out_flow);
}